// Round 22
// baseline (46.401 us; speedup 1.0000x reference)
//
#include <hip/hip_runtime.h>

#define HID 64
#define NTOK 66           // VOCAB_SIZE + 2
#define SEQ 64
#define WIN0 55           // SEQ_LEN - 1 - MEMORY_SLOTS
#define NW 8
#define LDS_STRIDE 72     // ushorts per table/h row (144B)
#define ITERS 8           // iterations per block (rows/block = 1024, grid = 512)
#define BLOCK 512         // 8 waves: 0-3 producers, 4-7 consumers
#define ROWS_PER_ITER 128 // 8 tiles x 16 rows
#define HOFF (2 * NTOK * LDS_STRIDE)       // ushort offset of h region
#define HBUF (ROWS_PER_ITER * LDS_STRIDE)  // one h buffer (ushorts)

typedef _Float16 half8 __attribute__((ext_vector_type(8)));
typedef unsigned short ushort8v __attribute__((ext_vector_type(8)));
typedef float float4v __attribute__((ext_vector_type(4)));

static __device__ __forceinline__ unsigned short f2h(float f) {
    _Float16 h = (_Float16)f;
    union { _Float16 h; unsigned short u; } v; v.h = h;
    return v.u;
}

// Kernel 1: tables T1[t][n] = b1[n] + sum_k emb[t][k]*W1[n][k]
//           T2[t][n] = 0.125 * sum_k emb[t][k]*W1[n][64+k]   (f16)
__global__ void build_tables(const float* __restrict__ embed,
                             const float* __restrict__ W1,
                             const float* __restrict__ b1,
                             unsigned short* __restrict__ tbl) {
    int b = blockIdx.x;      // 0..131
    int tb = b & 1;
    int t  = b >> 1;
    int n  = threadIdx.x;    // 0..63
    float acc = tb ? 0.0f : b1[n];
    const float* er = embed + t * HID;
    const float* wr = W1 + n * (2 * HID) + tb * HID;
#pragma unroll 8
    for (int k = 0; k < HID; ++k) acc += er[k] * wr[k];
    if (tb) acc *= 0.125f;
    tbl[tb * (NTOK * HID) + t * HID + n] = f2h(acc);
}

// Kernel 2: PRODUCER/CONSUMER WAVE SPECIALIZATION at 2 BLOCKS/CU.
// R21 (1 block/CU) proved the decoupling (46.5 -> 44.8us) but left each
// SIMD with exactly 1 producer + 1 consumer wave: no same-role TLP to hide
// the producer's 36-ds_read chain or the consumer's h-read->MFMA->store
// chain, and the block-wide barrier idles the faster role every iteration.
// grid=512 = 2 blocks/CU: each SIMD hosts 2P+2C from INDEPENDENT blocks --
// same-role latency hiding + the two blocks' barriers are unsynchronized,
// so one block's barrier bubble is absorbed by the other block's waves.
// LDS 56.3KB x 2 = 112.6KB <= 160KB; prologue paid 2x (~1us, R19 data).
__global__ __launch_bounds__(BLOCK, 2) void fused_forward(
    const int* __restrict__ seqs,
    const int* __restrict__ qtok,
    const float* __restrict__ W2,
    const float* __restrict__ b2,
    const unsigned short* __restrict__ tbl,
    float* __restrict__ out)
{
    // tables 19008 B + 2 h-buffers (128 rows x 144 B) 36864 B = 55872 B
    __shared__ unsigned short T_lds[HOFF + 2 * HBUF];

    int tid  = threadIdx.x;
    int wv   = tid >> 6;        // 0..7
    int l    = tid & 63;
    int lrow = l & 15;          // row within tile / W2 row within n-tile
    int lg   = l >> 4;          // k-chunk quarter / output col group
    int lk8  = lg * 8;          // k offset within 32-wide K chunk (ushorts)
    int tile0 = wv & 3;         // this wave's tiles: tile0 and tile0+4

    int blk0 = blockIdx.x * (ITERS * ROWS_PER_ITER);
    // producer token rows for its 2 tiles (iter t adds t*128)
    int prow0 = blk0 + tile0 * 16 + lrow;
    int prow1 = prow0 + 64;

    int qA0, qA1, qB0, qB1;
    int wA0[NW], wA1[NW], wB0[NW], wB1[NW];

// producer token loads for iter t_ (guard folds at compile time)
#define LOADT(S, t_) if ((t_) < ITERS) { \
    int r0_ = prow0 + (t_) * ROWS_PER_ITER; \
    int r1_ = prow1 + (t_) * ROWS_PER_ITER; \
    q##S##0 = qtok[r0_]; \
    q##S##1 = qtok[r1_]; \
    const int* s0_ = seqs + r0_ * SEQ + WIN0; \
    const int* s1_ = seqs + r1_ * SEQ + WIN0; \
    _Pragma("unroll") \
    for (int j = 0; j < NW; ++j) { w##S##0[j] = s0_[j]; w##S##1[j] = s1_[j]; } \
}

#define RD_T1(qq, koff) (*(const half8*)(T_lds + (qq) * LDS_STRIDE + (koff)))
#define RD_T2(ww, koff) (*(const half8*)(T_lds + NTOK * LDS_STRIDE + (ww) * LDS_STRIDE + (koff)))

// producer: gather+sum+relu both tiles, write 4 half8 rows to buf_
#define PRODUCE(S, buf_) { \
    unsigned short* hb_ = T_lds + HOFF + (buf_) * HBUF; \
    half8 s0_ = RD_T1(q##S##0, lk8); \
    half8 s1_ = RD_T1(q##S##0, 32 + lk8); \
    half8 u0_ = RD_T1(q##S##1, lk8); \
    half8 u1_ = RD_T1(q##S##1, 32 + lk8); \
    _Pragma("unroll") \
    for (int j = 0; j < NW; ++j) { \
        s0_ += RD_T2(w##S##0[j], lk8); \
        s1_ += RD_T2(w##S##0[j], 32 + lk8); \
        u0_ += RD_T2(w##S##1[j], lk8); \
        u1_ += RD_T2(w##S##1[j], 32 + lk8); \
    } \
    half8 z_ = (half8)(_Float16)0; \
    s0_ = __builtin_elementwise_max(s0_, z_); \
    s1_ = __builtin_elementwise_max(s1_, z_); \
    u0_ = __builtin_elementwise_max(u0_, z_); \
    u1_ = __builtin_elementwise_max(u1_, z_); \
    unsigned short* r0_ = hb_ + (tile0 * 16 + lrow) * LDS_STRIDE; \
    unsigned short* r1_ = hb_ + ((tile0 + 4) * 16 + lrow) * LDS_STRIDE; \
    *(half8*)(r0_ + lk8) = s0_; \
    *(half8*)(r0_ + 32 + lk8) = s1_; \
    *(half8*)(r1_ + lk8) = u0_; \
    *(half8*)(r1_ + 32 + lk8) = u1_; \
}

// consumer: read h fragments for both tiles, MFMA, store
#define CONSUME(t_, buf_) { \
    const unsigned short* hb_ = T_lds + HOFF + (buf_) * HBUF; \
    _Pragma("unroll") \
    for (int pt = 0; pt < 2; ++pt) { \
        int trow_ = (tile0 + pt * 4) * 16 + lrow; \
        half8 a0_ = *(const half8*)(hb_ + trow_ * LDS_STRIDE + lk8); \
        half8 a1_ = *(const half8*)(hb_ + trow_ * LDS_STRIDE + 32 + lk8); \
        float* op_ = out + (size_t)(blk0 + (t_) * ROWS_PER_ITER + trow_) * HID; \
        _Pragma("unroll") \
        for (int nt = 0; nt < 4; ++nt) { \
            float4v acc_ = __builtin_amdgcn_mfma_f32_16x16x32_f16(wfrag[nt][0], a0_, b2v[nt], 0, 0, 0); \
            acc_ = __builtin_amdgcn_mfma_f32_16x16x32_f16(wfrag[nt][1], a1_, acc_, 0, 0, 0); \
            *(float4v*)(op_ + nt * 16 + lg * 4) = acc_; \
        } \
    } \
}

// one iteration: consumers drain buf[t&1]; producers fill buf[(t+1)&1].
#define ITER_E(t_) { \
    if (wv >= 4) { CONSUME(t_, (t_) & 1); } \
    else if ((t_) + 1 < ITERS) { PRODUCE(B, ((t_) + 1) & 1); LOADT(B, (t_) + 3); } \
    __syncthreads(); \
}
#define ITER_O(t_) { \
    if (wv >= 4) { CONSUME(t_, (t_) & 1); } \
    else if ((t_) + 1 < ITERS) { PRODUCE(A, ((t_) + 1) & 1); LOADT(A, (t_) + 3); } \
    __syncthreads(); \
}

    // ---- (1) producers: iter 0/1 tokens (latency under fill+barrier) ----
    half8   wfrag[4][2];
    float4v b2v[4];
    if (wv < 4) {
        LOADT(A, 0);
        LOADT(B, 1);
    } else {
        // ---- (2) consumers: W2 A-fragments (whole 64x64, f16) + b2 ----
#pragma unroll
        for (int nt = 0; nt < 4; ++nt) {
            b2v[nt] = *(const float4v*)(b2 + nt * 16 + lg * 4);
#pragma unroll
            for (int kc = 0; kc < 2; ++kc) {
                const float* wp = W2 + (nt * 16 + lrow) * HID + kc * 32 + lk8;
                half8 f;
#pragma unroll
                for (int j = 0; j < 8; ++j) f[j] = (_Float16)wp[j];
                wfrag[nt][kc] = f;
            }
        }
    }

    // ---- (3) all waves: fill LDS tables (16B chunks; row stride 144B) ----
    for (int i = tid; i < 2 * NTOK * (HID / 8); i += BLOCK) {
        int tbi = i / (NTOK * 8);
        int rem = i - tbi * (NTOK * 8);
        int t   = rem >> 3;
        int kq  = (rem & 7) << 3;
        *(ushort8v*)(T_lds + tbi * (NTOK * LDS_STRIDE) + t * LDS_STRIDE + kq) =
            *(const ushort8v*)(tbl + tbi * (NTOK * HID) + t * HID + kq);
    }
    __syncthreads();

    // ---- (4) pipeline prologue: producers fill buf0 with iter 0's h ----
    if (wv < 4) {
        PRODUCE(A, 0);
        LOADT(A, 2);
    }
    __syncthreads();

    // ---- (5) 8 iterations: consume(t) || produce(t+1) ----
    ITER_E(0);  ITER_O(1);  ITER_E(2);  ITER_O(3);
    ITER_E(4);  ITER_O(5);  ITER_E(6);  ITER_O(7);

#undef LOADT
#undef RD_T1
#undef RD_T2
#undef PRODUCE
#undef CONSUME
#undef ITER_E
#undef ITER_O
}

extern "C" void kernel_launch(void* const* d_in, const int* in_sizes, int n_in,
                              void* d_out, int out_size, void* d_ws, size_t ws_size,
                              hipStream_t stream) {
    const int*   seqs  = (const int*)d_in[0];
    const int*   qtok  = (const int*)d_in[1];
    const float* embed = (const float*)d_in[2];
    const float* W1    = (const float*)d_in[3];
    const float* b1    = (const float*)d_in[4];
    const float* W2    = (const float*)d_in[5];
    const float* b2    = (const float*)d_in[6];
    float* out = (float*)d_out;
    unsigned short* tbl = (unsigned short*)d_ws;

    int B = in_sizes[0] / SEQ;

    build_tables<<<NTOK * 2, HID, 0, stream>>>(embed, W1, b1, tbl);

    int grid = B / (ITERS * ROWS_PER_ITER);
    fused_forward<<<grid, BLOCK, 0, stream>>>(seqs, qtok, W2, b2, tbl, out);
}

// Round 23
// 44.886 us; speedup vs baseline: 1.0338x; 1.0338x over previous
//
#include <hip/hip_runtime.h>

#define HID 64
#define NTOK 66           // VOCAB_SIZE + 2
#define SEQ 64
#define WIN0 55           // SEQ_LEN - 1 - MEMORY_SLOTS
#define NW 8
#define LDS_STRIDE 72     // ushorts per table/h row (144B)
#define ITERS 16          // iterations per block (rows/block = 2048, grid = 256)
#define BLOCK 512         // 8 waves: 0-3 producers, 4-7 consumers
#define ROWS_PER_ITER 128 // 8 tiles x 16 rows
#define HOFF (2 * NTOK * LDS_STRIDE)       // ushort offset of h region
#define HBUF (ROWS_PER_ITER * LDS_STRIDE)  // one h buffer (ushorts)

typedef _Float16 half8 __attribute__((ext_vector_type(8)));
typedef unsigned short ushort8v __attribute__((ext_vector_type(8)));
typedef float float4v __attribute__((ext_vector_type(4)));

static __device__ __forceinline__ unsigned short f2h(float f) {
    _Float16 h = (_Float16)f;
    union { _Float16 h; unsigned short u; } v; v.h = h;
    return v.u;
}

// Kernel 1: tables T1[t][n] = b1[n] + sum_k emb[t][k]*W1[n][k]
//           T2[t][n] = 0.125 * sum_k emb[t][k]*W1[n][64+k]   (f16)
__global__ void build_tables(const float* __restrict__ embed,
                             const float* __restrict__ W1,
                             const float* __restrict__ b1,
                             unsigned short* __restrict__ tbl) {
    int b = blockIdx.x;      // 0..131
    int tb = b & 1;
    int t  = b >> 1;
    int n  = threadIdx.x;    // 0..63
    float acc = tb ? 0.0f : b1[n];
    const float* er = embed + t * HID;
    const float* wr = W1 + n * (2 * HID) + tb * HID;
#pragma unroll 8
    for (int k = 0; k < HID; ++k) acc += er[k] * wr[k];
    if (tb) acc *= 0.125f;
    tbl[tb * (NTOK * HID) + t * HID + n] = f2h(acc);
}

// Kernel 2: PRODUCER/CONSUMER WAVE SPECIALIZATION + NO-VMCNT-DRAIN BARRIER.
// R21 proved the P/C decoupling (44.8us best). Its residual: __syncthreads
// emits s_waitcnt vmcnt(0) before s_barrier (HIP semantics) -> consumers
// drain their full 32KB store burst to L2 EVERY iteration; the store pipe
// empties and restarts instead of streaming (measured 6.7K cy/iter vs 4K
// HBM bound). The P/C handoff only needs lgkmcnt(0): producers' ds_writes
// must be visible; stores are write-once and never read -> may stay in
// flight across the barrier (T4: never drain vmcnt in the main loop).
// PC_BARRIER = s_waitcnt lgkmcnt(0) (with "memory" clobber = compiler
// fence) + raw s_barrier. Double-buffer safety: consumer's reads of
// buf[t&1] are consumed by its MFMAs before it reaches the barrier, so
// producers overwriting buf[t&1] at t+2 never race.
#define PC_BARRIER { \
    asm volatile("s_waitcnt lgkmcnt(0)" ::: "memory"); \
    __builtin_amdgcn_s_barrier(); \
}

__global__ __launch_bounds__(BLOCK, 2) void fused_forward(
    const int* __restrict__ seqs,
    const int* __restrict__ qtok,
    const float* __restrict__ W2,
    const float* __restrict__ b2,
    const unsigned short* __restrict__ tbl,
    float* __restrict__ out)
{
    // tables 19008 B + 2 h-buffers (128 rows x 144 B) 36864 B = 55872 B
    __shared__ unsigned short T_lds[HOFF + 2 * HBUF];

    int tid  = threadIdx.x;
    int wv   = tid >> 6;        // 0..7
    int l    = tid & 63;
    int lrow = l & 15;          // row within tile / W2 row within n-tile
    int lg   = l >> 4;          // k-chunk quarter / output col group
    int lk8  = lg * 8;          // k offset within 32-wide K chunk (ushorts)
    int tile0 = wv & 3;         // this wave's tiles: tile0 and tile0+4

    int blk0 = blockIdx.x * (ITERS * ROWS_PER_ITER);
    // producer token rows for its 2 tiles (iter t adds t*128)
    int prow0 = blk0 + tile0 * 16 + lrow;
    int prow1 = prow0 + 64;

    int qA0, qA1, qB0, qB1;
    int wA0[NW], wA1[NW], wB0[NW], wB1[NW];

// producer token loads for iter t_ (guard folds at compile time)
#define LOADT(S, t_) if ((t_) < ITERS) { \
    int r0_ = prow0 + (t_) * ROWS_PER_ITER; \
    int r1_ = prow1 + (t_) * ROWS_PER_ITER; \
    q##S##0 = qtok[r0_]; \
    q##S##1 = qtok[r1_]; \
    const int* s0_ = seqs + r0_ * SEQ + WIN0; \
    const int* s1_ = seqs + r1_ * SEQ + WIN0; \
    _Pragma("unroll") \
    for (int j = 0; j < NW; ++j) { w##S##0[j] = s0_[j]; w##S##1[j] = s1_[j]; } \
}

#define RD_T1(qq, koff) (*(const half8*)(T_lds + (qq) * LDS_STRIDE + (koff)))
#define RD_T2(ww, koff) (*(const half8*)(T_lds + NTOK * LDS_STRIDE + (ww) * LDS_STRIDE + (koff)))

// producer: gather+sum+relu both tiles, write 4 half8 rows to buf_
#define PRODUCE(S, buf_) { \
    unsigned short* hb_ = T_lds + HOFF + (buf_) * HBUF; \
    half8 s0_ = RD_T1(q##S##0, lk8); \
    half8 s1_ = RD_T1(q##S##0, 32 + lk8); \
    half8 u0_ = RD_T1(q##S##1, lk8); \
    half8 u1_ = RD_T1(q##S##1, 32 + lk8); \
    _Pragma("unroll") \
    for (int j = 0; j < NW; ++j) { \
        s0_ += RD_T2(w##S##0[j], lk8); \
        s1_ += RD_T2(w##S##0[j], 32 + lk8); \
        u0_ += RD_T2(w##S##1[j], lk8); \
        u1_ += RD_T2(w##S##1[j], 32 + lk8); \
    } \
    half8 z_ = (half8)(_Float16)0; \
    s0_ = __builtin_elementwise_max(s0_, z_); \
    s1_ = __builtin_elementwise_max(s1_, z_); \
    u0_ = __builtin_elementwise_max(u0_, z_); \
    u1_ = __builtin_elementwise_max(u1_, z_); \
    unsigned short* r0_ = hb_ + (tile0 * 16 + lrow) * LDS_STRIDE; \
    unsigned short* r1_ = hb_ + ((tile0 + 4) * 16 + lrow) * LDS_STRIDE; \
    *(half8*)(r0_ + lk8) = s0_; \
    *(half8*)(r0_ + 32 + lk8) = s1_; \
    *(half8*)(r1_ + lk8) = u0_; \
    *(half8*)(r1_ + 32 + lk8) = u1_; \
}

// consumer: read h fragments for both tiles, MFMA, store (stores are
// fire-and-forget: never drained inside the loop)
#define CONSUME(t_, buf_) { \
    const unsigned short* hb_ = T_lds + HOFF + (buf_) * HBUF; \
    _Pragma("unroll") \
    for (int pt = 0; pt < 2; ++pt) { \
        int trow_ = (tile0 + pt * 4) * 16 + lrow; \
        half8 a0_ = *(const half8*)(hb_ + trow_ * LDS_STRIDE + lk8); \
        half8 a1_ = *(const half8*)(hb_ + trow_ * LDS_STRIDE + 32 + lk8); \
        float* op_ = out + (size_t)(blk0 + (t_) * ROWS_PER_ITER + trow_) * HID; \
        _Pragma("unroll") \
        for (int nt = 0; nt < 4; ++nt) { \
            float4v acc_ = __builtin_amdgcn_mfma_f32_16x16x32_f16(wfrag[nt][0], a0_, b2v[nt], 0, 0, 0); \
            acc_ = __builtin_amdgcn_mfma_f32_16x16x32_f16(wfrag[nt][1], a1_, acc_, 0, 0, 0); \
            *(float4v*)(op_ + nt * 16 + lg * 4) = acc_; \
        } \
    } \
}

// one iteration: consumers drain buf[t&1]; producers fill buf[(t+1)&1].
// Barrier waits ONLY on LDS (lgkmcnt) -- stores stream across iterations.
#define ITER_E(t_) { \
    if (wv >= 4) { CONSUME(t_, (t_) & 1); } \
    else if ((t_) + 1 < ITERS) { PRODUCE(B, ((t_) + 1) & 1); LOADT(B, (t_) + 3); } \
    PC_BARRIER; \
}
#define ITER_O(t_) { \
    if (wv >= 4) { CONSUME(t_, (t_) & 1); } \
    else if ((t_) + 1 < ITERS) { PRODUCE(A, ((t_) + 1) & 1); LOADT(A, (t_) + 3); } \
    PC_BARRIER; \
}

    // ---- (1) producers: iter 0/1 tokens (latency under fill+barrier) ----
    half8   wfrag[4][2];
    float4v b2v[4];
    if (wv < 4) {
        LOADT(A, 0);
        LOADT(B, 1);
    } else {
        // ---- (2) consumers: W2 A-fragments (whole 64x64, f16) + b2 ----
#pragma unroll
        for (int nt = 0; nt < 4; ++nt) {
            b2v[nt] = *(const float4v*)(b2 + nt * 16 + lg * 4);
#pragma unroll
            for (int kc = 0; kc < 2; ++kc) {
                const float* wp = W2 + (nt * 16 + lrow) * HID + kc * 32 + lk8;
                half8 f;
#pragma unroll
                for (int j = 0; j < 8; ++j) f[j] = (_Float16)wp[j];
                wfrag[nt][kc] = f;
            }
        }
    }

    // ---- (3) all waves: fill LDS tables (16B chunks; row stride 144B) ----
    for (int i = tid; i < 2 * NTOK * (HID / 8); i += BLOCK) {
        int tbi = i / (NTOK * 8);
        int rem = i - tbi * (NTOK * 8);
        int t   = rem >> 3;
        int kq  = (rem & 7) << 3;
        *(ushort8v*)(T_lds + tbi * (NTOK * LDS_STRIDE) + t * LDS_STRIDE + kq) =
            *(const ushort8v*)(tbl + tbi * (NTOK * HID) + t * HID + kq);
    }
    __syncthreads();   // once: full drain acceptable here

    // ---- (4) pipeline prologue: producers fill buf0 with iter 0's h ----
    if (wv < 4) {
        PRODUCE(A, 0);
        LOADT(A, 2);
    }
    PC_BARRIER;

    // ---- (5) 16 iterations: consume(t) || produce(t+1) ----
    ITER_E(0);  ITER_O(1);  ITER_E(2);  ITER_O(3);
    ITER_E(4);  ITER_O(5);  ITER_E(6);  ITER_O(7);
    ITER_E(8);  ITER_O(9);  ITER_E(10); ITER_O(11);
    ITER_E(12); ITER_O(13); ITER_E(14); ITER_O(15);

#undef LOADT
#undef RD_T1
#undef RD_T2
#undef PRODUCE
#undef CONSUME
#undef ITER_E
#undef ITER_O
}

extern "C" void kernel_launch(void* const* d_in, const int* in_sizes, int n_in,
                              void* d_out, int out_size, void* d_ws, size_t ws_size,
                              hipStream_t stream) {
    const int*   seqs  = (const int*)d_in[0];
    const int*   qtok  = (const int*)d_in[1];
    const float* embed = (const float*)d_in[2];
    const float* W1    = (const float*)d_in[3];
    const float* b1    = (const float*)d_in[4];
    const float* W2    = (const float*)d_in[5];
    const float* b2    = (const float*)d_in[6];
    float* out = (float*)d_out;
    unsigned short* tbl = (unsigned short*)d_ws;

    int B = in_sizes[0] / SEQ;

    build_tables<<<NTOK * 2, HID, 0, stream>>>(embed, W1, b1, tbl);

    int grid = B / (ITERS * ROWS_PER_ITER);
    fused_forward<<<grid, BLOCK, 0, stream>>>(seqs, qtok, W2, b2, tbl, out);
}